// Round 15
// baseline (222.310 us; speedup 1.0000x reference)
//
#include <hip/hip_runtime.h>

// ---------- types ----------
typedef __bf16 bf16x8_t __attribute__((ext_vector_type(8)));
typedef bf16x8_t bf16x8 __attribute__((may_alias));
typedef float f32x4 __attribute__((ext_vector_type(4)));
typedef unsigned short u16x4 __attribute__((ext_vector_type(4)));
typedef unsigned short u16x8 __attribute__((ext_vector_type(8)));

#define DEV __device__ __forceinline__

DEV float b2f(unsigned short u) {
  union { unsigned int i; float f; } x; x.i = ((unsigned int)u) << 16; return x.f;
}
DEV unsigned short f2b(float f) {
  union { float f; unsigned int i; } x; x.f = f;
  return (unsigned short)((x.i + 0x7fffu + ((x.i >> 16) & 1u)) >> 16);
}

#define AS1(p) ((__attribute__((address_space(1))) void*)(p))
#define AS3(p) ((__attribute__((address_space(3))) void*)(p))

// ---------- ada (silu fused) ----------
__global__ __launch_bounds__(256) void k_ada(const float* __restrict__ cond,
                                             const float* __restrict__ w,
                                             const float* __restrict__ bias,
                                             float* __restrict__ out) {
  __shared__ float sc[4096];
  int tt = threadIdx.x;
#pragma unroll
  for (int i = 0; i < 16; ++i) {
    float v = cond[tt + i * 256];
    sc[tt + i * 256] = v / (1.f + __expf(-v));
  }
  __syncthreads();
  int j = blockIdx.x * 4 + (tt >> 6);
  int lane = tt & 63;
  const float* wr = w + (size_t)j * 1024;
  float s0 = 0.f, s1 = 0.f, s2 = 0.f, s3 = 0.f;
#pragma unroll
  for (int u = 0; u < 4; ++u) {
    int k = u * 256 + lane * 4;
    float4 a = *(const float4*)(wr + k);
    float4 c0 = *(const float4*)(sc + k);
    float4 c1 = *(const float4*)(sc + 1024 + k);
    float4 c2 = *(const float4*)(sc + 2048 + k);
    float4 c3 = *(const float4*)(sc + 3072 + k);
    s0 += a.x * c0.x + a.y * c0.y + a.z * c0.z + a.w * c0.w;
    s1 += a.x * c1.x + a.y * c1.y + a.z * c1.z + a.w * c1.w;
    s2 += a.x * c2.x + a.y * c2.y + a.z * c2.z + a.w * c2.w;
    s3 += a.x * c3.x + a.y * c3.y + a.z * c3.z + a.w * c3.w;
  }
#pragma unroll
  for (int o = 1; o < 64; o <<= 1) {
    s0 += __shfl_xor(s0, o); s1 += __shfl_xor(s1, o);
    s2 += __shfl_xor(s2, o); s3 += __shfl_xor(s3, o);
  }
  if (lane == 0) {
    float bb = bias[j];
    out[j] = s0 + bb;
    out[6144 + j] = s1 + bb;
    out[12288 + j] = s2 + bb;
    out[18432 + j] = s3 + bb;
  }
}

// ---------- all four weight casts in one launch ----------
__global__ __launch_bounds__(256) void k_castall(const float* __restrict__ q,
                                                 const float* __restrict__ p,
                                                 const float* __restrict__ f1,
                                                 const float* __restrict__ f2,
                                                 unsigned short* __restrict__ wq,
                                                 unsigned short* __restrict__ wp,
                                                 unsigned short* __restrict__ wf1,
                                                 unsigned short* __restrict__ wf2) {
  int i = blockIdx.x * 256 + threadIdx.x;
  for (int v = i; v < 3145728; v += 524288) {
    const float* s; unsigned short* d; int off;
    if (v < 786432) { s = q; d = wq; off = v; }
    else if (v < 1048576) { s = p; d = wp; off = v - 786432; }
    else if (v < 2097152) { s = f1; d = wf1; off = v - 1048576; }
    else { s = f2; d = wf2; off = v - 2097152; }
    float4 x = ((const float4*)s)[off];
    u16x4 o;
    o[0] = f2b(x.x); o[1] = f2b(x.y); o[2] = f2b(x.z); o[3] = f2b(x.w);
    *(u16x4*)(d + (size_t)off * 4) = o;
  }
}

__global__ __launch_bounds__(256) void k_ln_mod(const float* __restrict__ src,
                                                const float* __restrict__ ada,
                                                unsigned short* __restrict__ dst,
                                                int sidx, int hidx) {
  int row = blockIdx.x;
  int b = row >> 10;
  int t = threadIdx.x, lane = t & 63, wv = t >> 6;
  float4 v = *(const float4*)(src + (size_t)row * 1024 + t * 4);
  float s = v.x + v.y + v.z + v.w;
  float s2 = v.x * v.x + v.y * v.y + v.z * v.z + v.w * v.w;
#pragma unroll
  for (int o = 1; o < 64; o <<= 1) { s += __shfl_xor(s, o); s2 += __shfl_xor(s2, o); }
  __shared__ float red[8];
  if (lane == 0) { red[wv] = s; red[4 + wv] = s2; }
  __syncthreads();
  float ts = red[0] + red[1] + red[2] + red[3];
  float ts2 = red[4] + red[5] + red[6] + red[7];
  float mu = ts * (1.f / 1024.f);
  float var = ts2 * (1.f / 1024.f) - mu * mu;
  float rstd = rsqrtf(var + 1e-6f);
  const float* ar = ada + (size_t)b * 6144;
  float4 sc = *(const float4*)(ar + sidx * 1024 + t * 4);
  float4 sh = *(const float4*)(ar + hidx * 1024 + t * 4);
  u16x4 o;
  o[0] = f2b((v.x - mu) * rstd * (sc.x + 1.f) + sh.x);
  o[1] = f2b((v.y - mu) * rstd * (sc.y + 1.f) + sh.y);
  o[2] = f2b((v.z - mu) * rstd * (sc.z + 1.f) + sh.z);
  o[3] = f2b((v.w - mu) * rstd * (sc.w + 1.f) + sh.w);
  *(u16x4*)(dst + (size_t)row * 1024 + t * 4) = o;
}

// ---------- 128x128 4-wave GEMM, 2-buffer, 32KB LDS -> 4 blocks/CU ----------
// m97-mechanism maximized: small 4-wave sync domains, 3-4 co-resident blocks
// cover each other's drain stalls. Wave-tile 64x64 (acc[4][4]); per step
// 4 global_load_lds (A 2, B 2) + 8 ds_read_b128 + 16 MFMA; full NT unroll
// folds LDS offsets to immediates. Conflict-free chunk-XOR (source pre-swizzle
// (row>>1)&3, read XOR (fr>>1)&3 — congruent since 64*wm % 4 == 0).
// EPI 0: qkv -> fused q/k l2norm(+sm) to QN/KN + V buffer. EPI 2: fc1 gelu. EPI 4: partial.
template <int EPI, int SPLIT, int NT>
__global__ __launch_bounds__(256, 4) void k_gemm128(const unsigned short* __restrict__ A,
                                                    const unsigned short* __restrict__ W,
                                                    int N, int lda, int ldb,
                                                    const float* __restrict__ bias,
                                                    const float* __restrict__ qb,
                                                    const float* __restrict__ vb,
                                                    unsigned short* __restrict__ o0,
                                                    unsigned short* __restrict__ o1,
                                                    unsigned short* __restrict__ o2,
                                                    unsigned short* __restrict__ o3) {
  __shared__ unsigned short LDS[16384];  // 32 KiB: 2 bufs x {A[128][32] 8K | B[128][32] 8K}
  const int tid = threadIdx.x;
  const int wv = tid >> 6, lane = tid & 63;
  const int fr = lane & 15, fg = lane >> 4;
  const int wm = wv >> 1, wn = wv & 1;

  const int cpx = gridDim.x >> 3;
  int wid = ((int)blockIdx.x & 7) * cpx + ((int)blockIdx.x >> 3);
  int sp = 0;
  if (SPLIT > 1) { sp = wid & (SPLIT - 1); wid >>= 2; }
  const int nx = N >> 7;
  const int m0 = (wid / nx) * 128, n0 = (wid % nx) * 128;
  const int kbase = sp * (NT << 5);
  unsigned short* outp = (SPLIT > 1) ? (sp == 0 ? o0 : sp == 1 ? o1 : sp == 2 ? o2 : o3) : o0;

  // staging: 256 threads cover 64 rows x 4 chunks per instr; 2 instrs per operand
  const int sRow = tid >> 2;                       // 0..63
  const int sCh = (tid & 3) ^ ((tid >> 3) & 3);    // inverse involution, (row>>1)&3
  const unsigned short* aG = A + (size_t)(m0 + sRow) * lda + kbase + sCh * 8;
  const unsigned short* bG = W + (size_t)(n0 + sRow) * ldb + kbase + sCh * 8;

#define STQ(qi_)                                                                             \
  {                                                                                          \
    unsigned short* d_ = LDS + ((qi_) & 1) * 8192 + tid * 8;                                 \
    const int ko_ = (qi_) * 32;                                                              \
    __builtin_amdgcn_global_load_lds(AS1(aG + ko_), AS3(d_), 16, 0, 0);                      \
    __builtin_amdgcn_global_load_lds(AS1(aG + (size_t)64 * lda + ko_), AS3(d_ + 2048), 16, 0, 0); \
    __builtin_amdgcn_global_load_lds(AS1(bG + ko_), AS3(d_ + 4096), 16, 0, 0);               \
    __builtin_amdgcn_global_load_lds(AS1(bG + (size_t)64 * ldb + ko_), AS3(d_ + 6144), 16, 0, 0); \
  }

  const int rswz = (fr >> 1) & 3;
  const int xc = (fg ^ rswz) << 3;
  const int aOff = (wm * 64 + fr) * 32 + xc;
  const int bOff = 4096 + (wn * 64 + fr) * 32 + xc;

  f32x4 zz = {0.f, 0.f, 0.f, 0.f};
  f32x4 acc[4][4];
#pragma unroll
  for (int i = 0; i < 4; ++i)
#pragma unroll
    for (int j = 0; j < 4; ++j) acc[i][j] = zz;

  // prologue: stage tiles 0,1; land tile 0
  STQ(0); STQ(1);
  asm volatile("s_waitcnt vmcnt(4)" ::: "memory");
  __builtin_amdgcn_s_barrier();

#define LDSV(off) (*(const bf16x8*)(LDS + (off)))

#pragma unroll
  for (int t = 0; t < NT; ++t) {
    if (t >= 1 && t + 1 < NT) STQ(t + 1);
    const int REG = (t & 1) * 8192;  // compile-time per unrolled iteration
    bf16x8 b0 = LDSV(REG + bOff);
    bf16x8 b1 = LDSV(REG + bOff + 512);
    bf16x8 b2 = LDSV(REG + bOff + 1024);
    bf16x8 b3 = LDSV(REG + bOff + 1536);
    __builtin_amdgcn_s_setprio(1);
#pragma unroll
    for (int mi = 0; mi < 4; ++mi) {
      bf16x8 a = LDSV(REG + aOff + mi * 512);
      acc[mi][0] = __builtin_amdgcn_mfma_f32_16x16x32_bf16(a, b0, acc[mi][0], 0, 0, 0);
      acc[mi][1] = __builtin_amdgcn_mfma_f32_16x16x32_bf16(a, b1, acc[mi][1], 0, 0, 0);
      acc[mi][2] = __builtin_amdgcn_mfma_f32_16x16x32_bf16(a, b2, acc[mi][2], 0, 0, 0);
      acc[mi][3] = __builtin_amdgcn_mfma_f32_16x16x32_bf16(a, b3, acc[mi][3], 0, 0, 0);
    }
    __builtin_amdgcn_s_setprio(0);
    if (t < NT - 1) {
      asm volatile("s_waitcnt vmcnt(0)" ::: "memory");
      __builtin_amdgcn_s_barrier();
    }
  }

  // ---- epilogue ----
  if constexpr (EPI == 0) {
    const int nb = n0 + wn * 64;
    if (nb < 2048) {
      const bool isq = nb < 1024;
      const int h = (nb & 1023) >> 6;
      const float sm = isq ? __expf(fminf(bias[h], 4.6051701859880914f)) : 1.f;
      unsigned short* obase = isq ? o0 : o1;
#pragma unroll
      for (int mi = 0; mi < 4; ++mi) {
#pragma unroll
        for (int r = 0; r < 4; ++r) {
          float v0 = acc[mi][0][r], v1 = acc[mi][1][r], v2 = acc[mi][2][r], v3 = acc[mi][3][r];
          if (isq) {
            v0 += qb[nb + fr]; v1 += qb[nb + 16 + fr];
            v2 += qb[nb + 32 + fr]; v3 += qb[nb + 48 + fr];
          }
          float ss = v0 * v0 + v1 * v1 + v2 * v2 + v3 * v3;
          ss += __shfl_xor(ss, 1); ss += __shfl_xor(ss, 2);
          ss += __shfl_xor(ss, 4); ss += __shfl_xor(ss, 8);
          float scl = sm / fmaxf(sqrtf(ss), 1e-12f);
          int m = m0 + wm * 64 + mi * 16 + fg * 4 + r;
          int b = m >> 10, l = m & 1023;
          unsigned short* dst = obase + ((size_t)(b * 16 + h) * 1024 + l) * 64 + fr;
          dst[0]  = f2b(v0 * scl);
          dst[16] = f2b(v1 * scl);
          dst[32] = f2b(v2 * scl);
          dst[48] = f2b(v3 * scl);
        }
      }
    } else {
#pragma unroll
      for (int mi = 0; mi < 4; ++mi)
#pragma unroll
        for (int ni = 0; ni < 4; ++ni)
#pragma unroll
          for (int r = 0; r < 4; ++r) {
            int m = m0 + wm * 64 + mi * 16 + fg * 4 + r;
            int n = nb + ni * 16 + fr - 2048;
            o2[(size_t)m * 1024 + n] = f2b(acc[mi][ni][r] + vb[n]);
          }
    }
  } else {
#pragma unroll
    for (int mi = 0; mi < 4; ++mi) {
#pragma unroll
      for (int ni = 0; ni < 4; ++ni) {
#pragma unroll
        for (int r = 0; r < 4; ++r) {
          int m = m0 + wm * 64 + mi * 16 + fg * 4 + r;
          int n = n0 + wn * 64 + ni * 16 + fr;
          float v = acc[mi][ni][r];
          if constexpr (EPI == 2) {
            float z = v + bias[n];
            float u = z * (0.7978845608f + 0.0356774081f * z * z);
            float e = __expf(2.f * u);
            float th = 1.f - 2.f / (e + 1.f);
            outp[(size_t)m * N + n] = f2b(0.5f * z * (1.f + th));
          } else {
            outp[(size_t)m * N + n] = f2b(v);
          }
        }
      }
    }
  }
#undef STQ
#undef LDSV
}

// ---------- fc2 split-K reduce ----------
__global__ __launch_bounds__(256) void k_fc2red(const unsigned short* __restrict__ P0,
                                                const unsigned short* __restrict__ P1,
                                                const unsigned short* __restrict__ P2,
                                                const unsigned short* __restrict__ P3,
                                                const float* __restrict__ xmid,
                                                const float* __restrict__ bias,
                                                const float* __restrict__ ada,
                                                float* __restrict__ out) {
  size_t idx = ((size_t)blockIdx.x * 256 + threadIdx.x) * 8;
  int n = (int)(idx & 1023);
  int b = (int)(idx >> 20);
  u16x8 v0 = *(const u16x8*)(P0 + idx);
  u16x8 v1 = *(const u16x8*)(P1 + idx);
  u16x8 v2 = *(const u16x8*)(P2 + idx);
  u16x8 v3 = *(const u16x8*)(P3 + idx);
  const float* gp = ada + (size_t)b * 6144 + 1024 + n;
  const float* bp = bias + n;
  const float* xp = xmid + idx;
  float* op = out + idx;
#pragma unroll
  for (int i = 0; i < 8; ++i) {
    float sum = b2f(v0[i]) + b2f(v1[i]) + b2f(v2[i]) + b2f(v3[i]);
    op[i] = xp[i] + (sum + bp[i]) * gp[i];
  }
}

// ---------- 8-wave split-K GEMM (proj), NSTEPS template full-unroll ----------
template <int NSTEPS>
__global__ __launch_bounds__(512) void k_gemm8(const unsigned short* __restrict__ A,
                                               const unsigned short* __restrict__ W,
                                               int M, int N, int K,
                                               const float* __restrict__ bias,
                                               const float* __restrict__ resid,
                                               const float* __restrict__ ada,
                                               float* __restrict__ outp) {
  __shared__ unsigned short SM[49152];
  const int t = threadIdx.x, lane = t & 63, wv = t >> 6;
  const int grp = wv >> 2, w4 = wv & 3;
  const int wr = w4 >> 1, wc = w4 & 1;
  const int cpx = gridDim.x >> 3;
  const int orig = blockIdx.x;
  const int wid = (orig & 7) * cpx + (orig >> 3);
  const int nx = N >> 7;
  const int m0 = (wid / nx) * 128, n0 = (wid % nx) * 128;

  f32x4 zz = {0.f, 0.f, 0.f, 0.f};
  f32x4 acc[4][4];
#pragma unroll
  for (int i = 0; i < 4; ++i)
#pragma unroll
    for (int j = 0; j < 4; ++j) acc[i][j] = zz;

  const int Khalf = NSTEPS * 32;
  const int srow = lane >> 2, scol = (lane & 3) * 8;
  const int kbase = grp * Khalf;
  const unsigned short* aSrc0 = A + (size_t)(m0 + w4 * 16 + srow) * K + kbase + scol;
  const unsigned short* aSrc1 = aSrc0 + (size_t)64 * K;
  const unsigned short* bSrc0 = W + (size_t)(n0 + w4 * 16 + srow) * K + kbase + scol;
  const unsigned short* bSrc1 = bSrc0 + (size_t)64 * K;
  unsigned short* grpA = SM + grp * 24576;

  const int fr = lane & 15, fk = (lane >> 4) * 8;

#define STG8(buf_, k0_)                                                                            \
  {                                                                                                \
    __builtin_amdgcn_global_load_lds(AS1(aSrc0 + (k0_)), AS3(grpA + (buf_)*8192 + w4 * 512), 16, 0, 0); \
    __builtin_amdgcn_global_load_lds(AS1(aSrc1 + (k0_)), AS3(grpA + (buf_)*8192 + 2048 + w4 * 512), 16, 0, 0); \
    __builtin_amdgcn_global_load_lds(AS1(bSrc0 + (k0_)), AS3(grpA + (buf_)*8192 + 4096 + w4 * 512), 16, 0, 0); \
    __builtin_amdgcn_global_load_lds(AS1(bSrc1 + (k0_)), AS3(grpA + (buf_)*8192 + 6144 + w4 * 512), 16, 0, 0); \
  }

  STG8(0, 0);
  STG8(1, 32);
  asm volatile("s_waitcnt vmcnt(4)" ::: "memory");
  __builtin_amdgcn_s_barrier();

#pragma unroll
  for (int i = 0; i < NSTEPS; ++i) {
    const int buf = i % 3;
    if (i + 2 < NSTEPS) STG8((i + 2) % 3, (i + 2) * 32);
    const unsigned short* aRd = grpA + buf * 8192 + (wr * 64 + fr) * 32 + fk;
    const unsigned short* bRd = grpA + buf * 8192 + 4096 + (wc * 64 + fr) * 32 + fk;
    bf16x8 af[4], bfv[4];
#pragma unroll
    for (int q = 0; q < 4; ++q) af[q] = *(const bf16x8*)(aRd + q * 512);
#pragma unroll
    for (int q = 0; q < 4; ++q) bfv[q] = *(const bf16x8*)(bRd + q * 512);
    __builtin_amdgcn_s_setprio(1);
#pragma unroll
    for (int mi = 0; mi < 4; ++mi)
#pragma unroll
      for (int ni = 0; ni < 4; ++ni)
        acc[mi][ni] = __builtin_amdgcn_mfma_f32_16x16x32_bf16(af[mi], bfv[ni], acc[mi][ni], 0, 0, 0);
    __builtin_amdgcn_s_setprio(0);
    if (i < NSTEPS - 1) {
      if (i + 2 < NSTEPS) {
        asm volatile("s_waitcnt vmcnt(4)" ::: "memory");
      } else {
        asm volatile("s_waitcnt vmcnt(0)" ::: "memory");
      }
      __builtin_amdgcn_s_barrier();
    }
  }
  __syncthreads();

  float* xch = (float*)SM;
#pragma unroll
  for (int c = 0; c < 16; ++c) {
    if (grp == 1)
      *(f32x4*)&xch[c * 1024 + (w4 * 64 + lane) * 4] = acc[c >> 2][c & 3];
  }
  __syncthreads();
  if (grp == 1) return;
#pragma unroll
  for (int c = 0; c < 16; ++c) {
    f32x4 p = *(const f32x4*)&xch[c * 1024 + (w4 * 64 + lane) * 4];
    acc[c >> 2][c & 3] += p;
  }

  const int fg = lane >> 4;
#pragma unroll
  for (int mi = 0; mi < 4; ++mi) {
#pragma unroll
    for (int ni = 0; ni < 4; ++ni) {
#pragma unroll
      for (int r = 0; r < 4; ++r) {
        int m = m0 + wr * 64 + mi * 16 + fg * 4 + r;
        int n = n0 + wc * 64 + ni * 16 + fr;
        float v = acc[mi][ni][r];
        float g = ada[(size_t)(m >> 10) * 6144 + n];
        outp[(size_t)m * N + n] = resid[(size_t)m * N + n] + (v + bias[n]) * g;
      }
    }
  }
#undef STG8
}

// ---------- V transpose with k-slot permutation (reads compact V buffer) ----------
__global__ __launch_bounds__(256) void k_vtrans(const unsigned short* __restrict__ V,
                                                unsigned short* __restrict__ Vt) {
  int bh = blockIdx.y, b = bh >> 4, h = bh & 15;
  int l0 = blockIdx.x * 64;
  __shared__ unsigned short tile[64][72];
  int t = threadIdx.x;
  int lr = t >> 2, dp = (t & 3) * 16;
  const unsigned short* src = V + (size_t)(b * 1024 + l0 + lr) * 1024 + h * 64 + dp;
  *(u16x8*)&tile[lr][dp] = *(const u16x8*)src;
  *(u16x8*)&tile[lr][dp + 8] = *(const u16x8*)(src + 8);
  __syncthreads();
  int d = t >> 2, lp = (t & 3) * 16;
  unsigned short ov[16];
#pragma unroll
  for (int j = 0; j < 16; ++j) {
    int p = lp + j;
    int l = ((p >> 5) * 2 + ((p >> 2) & 1)) * 16 + ((p >> 3) & 3) * 4 + (p & 3);
    ov[j] = tile[l][d];
  }
  unsigned short* dst = Vt + ((size_t)bh * 64 + d) * 1024 + l0 + lp;
  *(u16x8*)dst = *(u16x8*)&ov[0];
  *(u16x8*)(dst + 8) = *(u16x8*)&ov[8];
}

// ---------- flash attention ----------
__global__ __launch_bounds__(256) void k_attn(const unsigned short* __restrict__ Qn,
                                              const unsigned short* __restrict__ Kn,
                                              const unsigned short* __restrict__ Vt,
                                              const float* __restrict__ smul,
                                              unsigned short* __restrict__ O) {
  const int qt = blockIdx.x, bh = blockIdx.y;
  const int b = bh >> 4, h = bh & 15;
  const int t = threadIdx.x, lane = t & 63, wv = t >> 6;
  const int fr = lane & 15, fg = lane >> 4;
  __shared__ unsigned short Kb[2][4096];
  __shared__ unsigned short Vb[2][4096];

  const int q0 = qt * 128 + wv * 32;
  const unsigned short* qp = Qn + ((size_t)bh * 1024 + q0 + fr) * 64 + fg * 8;
  bf16x8 qf00 = *(const bf16x8*)qp;
  bf16x8 qf01 = *(const bf16x8*)(qp + 32);
  bf16x8 qf10 = *(const bf16x8*)(qp + 1024);
  bf16x8 qf11 = *(const bf16x8*)(qp + 1024 + 32);

  const float M = __expf(fminf(smul[h], 4.6051701859880914f));

  const int srow = lane >> 3, sc = lane & 7;
  const int xr = (sc ^ srow) * 8;
  const unsigned short* kp0 = Kn + (size_t)bh * 65536 + (size_t)(wv * 16 + srow) * 64 + xr;
  const unsigned short* kp1 = kp0 + 8 * 64;
  const unsigned short* vp0 = Vt + (size_t)bh * 65536 + (size_t)(wv * 16 + srow) * 1024 + xr;
  const unsigned short* vp1 = vp0 + 8 * 1024;

  f32x4 zz = {0.f, 0.f, 0.f, 0.f};
  f32x4 oa0[4], oa1[4];
#pragma unroll
  for (int i = 0; i < 4; ++i) { oa0[i] = zz; oa1[i] = zz; }
  float ls0 = 0.f, ls1 = 0.f;

  {
    unsigned short* kd = &Kb[0][wv * 1024];
    unsigned short* vd = &Vb[0][wv * 1024];
    __builtin_amdgcn_global_load_lds(AS1(kp0), AS3(kd), 16, 0, 0);
    __builtin_amdgcn_global_load_lds(AS1(kp1), AS3(kd + 512), 16, 0, 0);
    __builtin_amdgcn_global_load_lds(AS1(vp0), AS3(vd), 16, 0, 0);
    __builtin_amdgcn_global_load_lds(AS1(vp1), AS3(vd + 512), 16, 0, 0);
  }
  __syncthreads();

  int cur = 0;
  for (int kv = 0; kv < 1024; kv += 64) {
    const int nxt = cur ^ 1;
    if (kv + 64 < 1024) {
      const int ko = (kv + 64) * 64;
      const int vo = kv + 64;
      unsigned short* kd = &Kb[nxt][wv * 1024];
      unsigned short* vd = &Vb[nxt][wv * 1024];
      __builtin_amdgcn_global_load_lds(AS1(kp0 + ko), AS3(kd), 16, 0, 0);
      __builtin_amdgcn_global_load_lds(AS1(kp1 + ko), AS3(kd + 512), 16, 0, 0);
      __builtin_amdgcn_global_load_lds(AS1(vp0 + vo), AS3(vd), 16, 0, 0);
      __builtin_amdgcn_global_load_lds(AS1(vp1 + vo), AS3(vd + 512), 16, 0, 0);
    }

    f32x4 s0[4], s1[4];
    __builtin_amdgcn_s_setprio(1);
#pragma unroll
    for (int ct = 0; ct < 4; ++ct) {
      const int row = ct * 16 + fr, r7 = row & 7;
      const unsigned short* kr = &Kb[cur][row * 64];
      bf16x8 kf0 = *(const bf16x8*)(kr + ((fg ^ r7) << 3));
      bf16x8 kf1 = *(const bf16x8*)(kr + (((4 + fg) ^ r7) << 3));
      f32x4 z0 = __builtin_amdgcn_mfma_f32_16x16x32_bf16(kf0, qf00, zz, 0, 0, 0);
      s0[ct] = __builtin_amdgcn_mfma_f32_16x16x32_bf16(kf1, qf01, z0, 0, 0, 0);
      f32x4 z1 = __builtin_amdgcn_mfma_f32_16x16x32_bf16(kf0, qf10, zz, 0, 0, 0);
      s1[ct] = __builtin_amdgcn_mfma_f32_16x16x32_bf16(kf1, qf11, z1, 0, 0, 0);
    }
    __builtin_amdgcn_s_setprio(0);

    bf16x8 pa0[2], pa1[2];
#pragma unroll
    for (int kg = 0; kg < 2; ++kg) {
      bf16x8 a0, a1;
#pragma unroll
      for (int c2 = 0; c2 < 2; ++c2) {
#pragma unroll
        for (int r = 0; r < 4; ++r) {
          float e0 = __expf(s0[kg * 2 + c2][r] - M);
          float e1 = __expf(s1[kg * 2 + c2][r] - M);
          ls0 += e0; ls1 += e1;
          a0[c2 * 4 + r] = (__bf16)e0;
          a1[c2 * 4 + r] = (__bf16)e1;
        }
      }
      pa0[kg] = a0; pa1[kg] = a1;
    }

    __builtin_amdgcn_s_setprio(1);
#pragma unroll
    for (int kg = 0; kg < 2; ++kg) {
#pragma unroll
      for (int dt = 0; dt < 4; ++dt) {
        const int row = dt * 16 + fr, r7 = row & 7;
        bf16x8 vf = *(const bf16x8*)(&Vb[cur][row * 64] + ((((kg << 2) + fg) ^ r7) << 3));
        oa0[dt] = __builtin_amdgcn_mfma_f32_16x16x32_bf16(pa0[kg], vf, oa0[dt], 0, 0, 0);
        oa1[dt] = __builtin_amdgcn_mfma_f32_16x16x32_bf16(pa1[kg], vf, oa1[dt], 0, 0, 0);
      }
    }
    __builtin_amdgcn_s_setprio(0);
    __syncthreads();
    cur = nxt;
  }

  ls0 += __shfl_xor(ls0, 16); ls0 += __shfl_xor(ls0, 32);
  ls1 += __shfl_xor(ls1, 16); ls1 += __shfl_xor(ls1, 32);

#pragma unroll
  for (int r = 0; r < 4; ++r) {
    float i0 = 1.f / __shfl(ls0, fg * 4 + r);
    float i1 = 1.f / __shfl(ls1, fg * 4 + r);
    unsigned short* ob = O + ((size_t)(b * 1024 + q0 + fg * 4 + r)) * 1024 + h * 64 + fr;
#pragma unroll
    for (int dt = 0; dt < 4; ++dt) {
      ob[dt * 16] = f2b(oa0[dt][r] * i0);
      ob[(size_t)16 * 1024 + dt * 16] = f2b(oa1[dt][r] * i1);
    }
  }
}

// ---------- launch ----------
extern "C" void kernel_launch(void* const* d_in, const int* in_sizes, int n_in,
                              void* d_out, int out_size, void* d_ws, size_t ws_size,
                              hipStream_t stream) {
  const float* x        = (const float*)d_in[0];
  const float* cond     = (const float*)d_in[1];
  const float* qkv_w    = (const float*)d_in[2];
  const float* q_bias   = (const float*)d_in[3];
  const float* v_bias   = (const float*)d_in[4];
  const float* scale_mul= (const float*)d_in[5];
  const float* proj_w   = (const float*)d_in[6];
  const float* proj_b   = (const float*)d_in[7];
  const float* ada_w    = (const float*)d_in[8];
  const float* ada_b    = (const float*)d_in[9];
  const float* fc1_w    = (const float*)d_in[10];
  const float* fc1_b    = (const float*)d_in[11];
  const float* fc2_w    = (const float*)d_in[12];
  const float* fc2_b    = (const float*)d_in[13];
  float* out = (float*)d_out;
  char* ws = (char*)d_ws;

  // ---- workspace map (lifetimes annotated; no live overlaps) ----
  unsigned short* WQ   = (unsigned short*)(ws + 0);          // dead after qkv
  unsigned short* WP   = (unsigned short*)(ws + 6291456);    // dead after proj
  unsigned short* WF1  = (unsigned short*)(ws + 8388608);    // dead after fc1
  unsigned short* WF2  = (unsigned short*)(ws + 16777216);   // dead after fc2 gemm
  float*          ADA  = (float*)(ws + 25182208);            // live throughout
  unsigned short* X1   = (unsigned short*)(ws + 25280512);   // dead after fc1
  unsigned short* VB   = (unsigned short*)(ws + 33669120);   // dead after vtrans
  float*          XMID = (float*)(ws + 42057728);            // live till fc2red
  unsigned short* QN   = (unsigned short*)(ws + 58834944);   // dead after attn
  unsigned short* KN   = (unsigned short*)(ws + 67223552);   // dead after attn
  unsigned short* VT   = (unsigned short*)(ws + 75612160);   // dead after attn
  unsigned short* OB   = (unsigned short*)(ws + 84000768);   // dead after proj
  unsigned short* HB   = (unsigned short*)(ws + 58834944);   // over QN/KN/VT/OB (dead by fc1)
  unsigned short* FP0  = (unsigned short*)(ws + 0);          // over WQ+WP (dead after proj)
  unsigned short* FP1  = (unsigned short*)(ws + 8388608);    // over WF1 (dead after fc1)
  unsigned short* FP2  = (unsigned short*)(ws + 25280512);   // over X1 (dead after fc1)
  unsigned short* FP3  = (unsigned short*)(ws + 33669120);   // over VB (dead after vtrans)

  (void)in_sizes; (void)n_in; (void)out_size; (void)ws_size;

  k_ada<<<1536, 256, 0, stream>>>(cond, ada_w, ada_b, ADA);
  k_castall<<<2048, 256, 0, stream>>>(qkv_w, proj_w, fc1_w, fc2_w, WQ, WP, WF1, WF2);

  k_ln_mod<<<4096, 256, 0, stream>>>(x, ADA, X1, 2, 4);
  // qkv: 32 m-tiles x 24 n-tiles = 768 blocks (3/CU)
  k_gemm128<0, 1, 32><<<768, 256, 0, stream>>>(X1, WQ, 3072, 1024, 1024,
                                               scale_mul, q_bias, v_bias, QN, KN, VB, nullptr);
  k_vtrans<<<dim3(16, 64), 256, 0, stream>>>(VB, VT);
  k_attn<<<dim3(8, 64), 256, 0, stream>>>(QN, KN, VT, scale_mul, OB);
  k_gemm8<16><<<256, 512, 0, stream>>>(OB, WP, 4096, 1024, 1024,
                                       proj_b, x, ADA, XMID);
  k_ln_mod<<<4096, 256, 0, stream>>>(XMID, ADA, X1, 3, 5);
  // fc1: 32 x 32 = 1024 blocks (4/CU)
  k_gemm128<2, 1, 32><<<1024, 256, 0, stream>>>(X1, WF1, 4096, 1024, 1024,
                                                fc1_b, nullptr, nullptr, HB, nullptr, nullptr, nullptr);
  // fc2: split-K=4 -> 32 x 8 x 4 = 1024 blocks (4/CU)
  k_gemm128<4, 4, 32><<<1024, 256, 0, stream>>>(HB, WF2, 1024, 4096, 4096,
                                                nullptr, nullptr, nullptr, FP0, FP1, FP2, FP3);
  k_fc2red<<<2048, 256, 0, stream>>>(FP0, FP1, FP2, FP3, XMID, fc2_b, ADA, out);
}

// Round 16
// 204.080 us; speedup vs baseline: 1.0893x; 1.0893x over previous
//
#include <hip/hip_runtime.h>

// ---------- types ----------
typedef __bf16 bf16x8_t __attribute__((ext_vector_type(8)));
typedef bf16x8_t bf16x8 __attribute__((may_alias));
typedef float f32x4 __attribute__((ext_vector_type(4)));
typedef unsigned short u16x4 __attribute__((ext_vector_type(4)));
typedef unsigned short u16x8 __attribute__((ext_vector_type(8)));

#define DEV __device__ __forceinline__

DEV float b2f(unsigned short u) {
  union { unsigned int i; float f; } x; x.i = ((unsigned int)u) << 16; return x.f;
}
DEV unsigned short f2b(float f) {
  union { float f; unsigned int i; } x; x.f = f;
  return (unsigned short)((x.i + 0x7fffu + ((x.i >> 16) & 1u)) >> 16);
}

#define AS1(p) ((__attribute__((address_space(1))) void*)(p))
#define AS3(p) ((__attribute__((address_space(3))) void*)(p))

// ---------- ada (silu fused) ----------
__global__ __launch_bounds__(256) void k_ada(const float* __restrict__ cond,
                                             const float* __restrict__ w,
                                             const float* __restrict__ bias,
                                             float* __restrict__ out) {
  __shared__ float sc[4096];
  int tt = threadIdx.x;
#pragma unroll
  for (int i = 0; i < 16; ++i) {
    float v = cond[tt + i * 256];
    sc[tt + i * 256] = v / (1.f + __expf(-v));
  }
  __syncthreads();
  int j = blockIdx.x * 4 + (tt >> 6);
  int lane = tt & 63;
  const float* wr = w + (size_t)j * 1024;
  float s0 = 0.f, s1 = 0.f, s2 = 0.f, s3 = 0.f;
#pragma unroll
  for (int u = 0; u < 4; ++u) {
    int k = u * 256 + lane * 4;
    float4 a = *(const float4*)(wr + k);
    float4 c0 = *(const float4*)(sc + k);
    float4 c1 = *(const float4*)(sc + 1024 + k);
    float4 c2 = *(const float4*)(sc + 2048 + k);
    float4 c3 = *(const float4*)(sc + 3072 + k);
    s0 += a.x * c0.x + a.y * c0.y + a.z * c0.z + a.w * c0.w;
    s1 += a.x * c1.x + a.y * c1.y + a.z * c1.z + a.w * c1.w;
    s2 += a.x * c2.x + a.y * c2.y + a.z * c2.z + a.w * c2.w;
    s3 += a.x * c3.x + a.y * c3.y + a.z * c3.z + a.w * c3.w;
  }
#pragma unroll
  for (int o = 1; o < 64; o <<= 1) {
    s0 += __shfl_xor(s0, o); s1 += __shfl_xor(s1, o);
    s2 += __shfl_xor(s2, o); s3 += __shfl_xor(s3, o);
  }
  if (lane == 0) {
    float bb = bias[j];
    out[j] = s0 + bb;
    out[6144 + j] = s1 + bb;
    out[12288 + j] = s2 + bb;
    out[18432 + j] = s3 + bb;
  }
}

// ---------- all four weight casts in one launch ----------
__global__ __launch_bounds__(256) void k_castall(const float* __restrict__ q,
                                                 const float* __restrict__ p,
                                                 const float* __restrict__ f1,
                                                 const float* __restrict__ f2,
                                                 unsigned short* __restrict__ wq,
                                                 unsigned short* __restrict__ wp,
                                                 unsigned short* __restrict__ wf1,
                                                 unsigned short* __restrict__ wf2) {
  int i = blockIdx.x * 256 + threadIdx.x;
  for (int v = i; v < 3145728; v += 524288) {
    const float* s; unsigned short* d; int off;
    if (v < 786432) { s = q; d = wq; off = v; }
    else if (v < 1048576) { s = p; d = wp; off = v - 786432; }
    else if (v < 2097152) { s = f1; d = wf1; off = v - 1048576; }
    else { s = f2; d = wf2; off = v - 2097152; }
    float4 x = ((const float4*)s)[off];
    u16x4 o;
    o[0] = f2b(x.x); o[1] = f2b(x.y); o[2] = f2b(x.z); o[3] = f2b(x.w);
    *(u16x4*)(d + (size_t)off * 4) = o;
  }
}

__global__ __launch_bounds__(256) void k_ln_mod(const float* __restrict__ src,
                                                const float* __restrict__ ada,
                                                unsigned short* __restrict__ dst,
                                                int sidx, int hidx) {
  int row = blockIdx.x;
  int b = row >> 10;
  int t = threadIdx.x, lane = t & 63, wv = t >> 6;
  float4 v = *(const float4*)(src + (size_t)row * 1024 + t * 4);
  float s = v.x + v.y + v.z + v.w;
  float s2 = v.x * v.x + v.y * v.y + v.z * v.z + v.w * v.w;
#pragma unroll
  for (int o = 1; o < 64; o <<= 1) { s += __shfl_xor(s, o); s2 += __shfl_xor(s2, o); }
  __shared__ float red[8];
  if (lane == 0) { red[wv] = s; red[4 + wv] = s2; }
  __syncthreads();
  float ts = red[0] + red[1] + red[2] + red[3];
  float ts2 = red[4] + red[5] + red[6] + red[7];
  float mu = ts * (1.f / 1024.f);
  float var = ts2 * (1.f / 1024.f) - mu * mu;
  float rstd = rsqrtf(var + 1e-6f);
  const float* ar = ada + (size_t)b * 6144;
  float4 sc = *(const float4*)(ar + sidx * 1024 + t * 4);
  float4 sh = *(const float4*)(ar + hidx * 1024 + t * 4);
  u16x4 o;
  o[0] = f2b((v.x - mu) * rstd * (sc.x + 1.f) + sh.x);
  o[1] = f2b((v.y - mu) * rstd * (sc.y + 1.f) + sh.y);
  o[2] = f2b((v.z - mu) * rstd * (sc.z + 1.f) + sh.z);
  o[3] = f2b((v.w - mu) * rstd * (sc.w + 1.f) + sh.w);
  *(u16x4*)(dst + (size_t)row * 1024 + t * 4) = o;
}

// ---------- 256x128 8-wave GEMM, 3-region rotation, 2 blocks/CU, FULL UNROLL ----------
// r14 proven core (48us/GEMM, MfmaUtil 29.6). EPI 0 now ALSO writes V^T directly
// (k-slot permuted for attn's B-fragment layout): for lane (fr,fg), frag (mi,ni,r),
// p = (mi>>1)*32 + fg*8 + (mi&1)*4 + r satisfies phys(p) = mi*16+fg*4+r = l&63,
// and r=0..3 are contiguous -> one u16x4 store. Kills k_vtrans + VB round-trip.
// EPI 2: fc1 (+bias, tanh-GELU, bf16). EPI 4: raw bf16 partial (fc2 split-K).
template <int EPI, int SPLIT, int NT>
__global__ __launch_bounds__(512, 4) void k_gemm256(const unsigned short* __restrict__ A,
                                                    const unsigned short* __restrict__ W,
                                                    int N, int lda, int ldb,
                                                    const float* __restrict__ bias,
                                                    const float* __restrict__ qb,
                                                    const float* __restrict__ vb,
                                                    unsigned short* __restrict__ o0,
                                                    unsigned short* __restrict__ o1,
                                                    unsigned short* __restrict__ o2,
                                                    unsigned short* __restrict__ o3) {
  __shared__ unsigned short LDS[36864];  // 72 KiB: 3 regions x {A[256][32] | B[128][32]}
  const int tid = threadIdx.x;
  const int wv = tid >> 6, lane = tid & 63;
  const int fr = lane & 15, fg = lane >> 4;
  const int wm = wv >> 1, wn = wv & 1;

  const int cpx = gridDim.x >> 3;
  int wid = ((int)blockIdx.x & 7) * cpx + ((int)blockIdx.x >> 3);
  int sp = 0;
  if (SPLIT > 1) { sp = wid & (SPLIT - 1); wid >>= 2; }
  const int nx = N >> 7;
  const int m0 = (wid / nx) * 256, n0 = (wid % nx) * 128;
  const int kbase = sp * (NT << 5);
  unsigned short* outp = (SPLIT > 1) ? (sp == 0 ? o0 : sp == 1 ? o1 : sp == 2 ? o2 : o3) : o0;

  const int sRow = tid >> 2;
  const int sCh = (tid & 3) ^ ((tid >> 3) & 3);
  const unsigned short* aG = A + (size_t)(m0 + sRow) * lda + kbase + sCh * 8;
  const unsigned short* bG = W + (size_t)(n0 + sRow) * ldb + kbase + sCh * 8;

#define STQ3(qi_)                                                                            \
  {                                                                                          \
    unsigned short* d_ = LDS + ((qi_) % 3) * 12288 + tid * 8;                                \
    const int ko_ = (qi_) * 32;                                                              \
    __builtin_amdgcn_global_load_lds(AS1(aG + ko_), AS3(d_), 16, 0, 0);                      \
    __builtin_amdgcn_global_load_lds(AS1(aG + (size_t)128 * lda + ko_), AS3(d_ + 4096), 16, 0, 0); \
    __builtin_amdgcn_global_load_lds(AS1(bG + ko_), AS3(d_ + 8192), 16, 0, 0);               \
  }

  const int rswz = (fr >> 1) & 3;
  const int xc = (fg ^ rswz) << 3;
  const int aOff = (wm * 64 + fr) * 32 + xc;
  const int bOff = 8192 + (wn * 64 + fr) * 32 + xc;

  f32x4 zz = {0.f, 0.f, 0.f, 0.f};
  f32x4 acc[4][4];
#pragma unroll
  for (int i = 0; i < 4; ++i)
#pragma unroll
    for (int j = 0; j < 4; ++j) acc[i][j] = zz;

  STQ3(0); STQ3(1); STQ3(2);
  asm volatile("s_waitcnt vmcnt(6)" ::: "memory");
  __builtin_amdgcn_s_barrier();

#define LDSV(off) (*(const bf16x8*)(LDS + (off)))

#pragma unroll
  for (int t = 0; t < NT; ++t) {
    if (t >= 1 && t + 2 < NT) STQ3(t + 2);
    const int REG = (t % 3) * 12288;  // compile-time per unrolled iteration
    bf16x8 b0 = LDSV(REG + bOff);
    bf16x8 b1 = LDSV(REG + bOff + 512);
    bf16x8 b2 = LDSV(REG + bOff + 1024);
    bf16x8 b3 = LDSV(REG + bOff + 1536);
    __builtin_amdgcn_s_setprio(1);
#pragma unroll
    for (int mi = 0; mi < 4; ++mi) {
      bf16x8 a = LDSV(REG + aOff + mi * 512);
      acc[mi][0] = __builtin_amdgcn_mfma_f32_16x16x32_bf16(a, b0, acc[mi][0], 0, 0, 0);
      acc[mi][1] = __builtin_amdgcn_mfma_f32_16x16x32_bf16(a, b1, acc[mi][1], 0, 0, 0);
      acc[mi][2] = __builtin_amdgcn_mfma_f32_16x16x32_bf16(a, b2, acc[mi][2], 0, 0, 0);
      acc[mi][3] = __builtin_amdgcn_mfma_f32_16x16x32_bf16(a, b3, acc[mi][3], 0, 0, 0);
    }
    __builtin_amdgcn_s_setprio(0);
    if (t < NT - 1) {
      if (t + 2 < NT) {
        asm volatile("s_waitcnt vmcnt(3)" ::: "memory");
      } else {
        asm volatile("s_waitcnt vmcnt(0)" ::: "memory");
      }
      __builtin_amdgcn_s_barrier();
    }
  }

  // ---- epilogue ----
  if constexpr (EPI == 0) {
    const int nb = n0 + wn * 64;
    if (nb < 2048) {
      const bool isq = nb < 1024;
      const int h = (nb & 1023) >> 6;
      const float sm = isq ? __expf(fminf(bias[h], 4.6051701859880914f)) : 1.f;
      unsigned short* obase = isq ? o0 : o1;
#pragma unroll
      for (int mi = 0; mi < 4; ++mi) {
#pragma unroll
        for (int r = 0; r < 4; ++r) {
          float v0 = acc[mi][0][r], v1 = acc[mi][1][r], v2 = acc[mi][2][r], v3 = acc[mi][3][r];
          if (isq) {
            v0 += qb[nb + fr]; v1 += qb[nb + 16 + fr];
            v2 += qb[nb + 32 + fr]; v3 += qb[nb + 48 + fr];
          }
          float ss = v0 * v0 + v1 * v1 + v2 * v2 + v3 * v3;
          ss += __shfl_xor(ss, 1); ss += __shfl_xor(ss, 2);
          ss += __shfl_xor(ss, 4); ss += __shfl_xor(ss, 8);
          float scl = sm / fmaxf(sqrtf(ss), 1e-12f);
          int m = m0 + wm * 64 + mi * 16 + fg * 4 + r;
          int b = m >> 10, l = m & 1023;
          unsigned short* dst = obase + ((size_t)(b * 16 + h) * 1024 + l) * 64 + fr;
          dst[0]  = f2b(v0 * scl);
          dst[16] = f2b(v1 * scl);
          dst[32] = f2b(v2 * scl);
          dst[48] = f2b(v3 * scl);
        }
      }
    } else {
      // V: write V^T directly (k-slot permuted). o2 = Vt[bh][d][l'].
      const int nv = nb - 2048;               // 64-aligned head-dim block base
      const int h = nv >> 6;
      const int bq = m0 >> 10;
      const int baseL = (m0 & 1023) + wm * 64;  // 64-aligned l-block base
#pragma unroll
      for (int mi = 0; mi < 4; ++mi) {
#pragma unroll
        for (int ni = 0; ni < 4; ++ni) {
          u16x4 ov;
#pragma unroll
          for (int r = 0; r < 4; ++r) ov[r] = f2b(acc[mi][ni][r] + vb[nv + ni * 16 + fr]);
          const int p = (mi >> 1) * 32 + fg * 8 + (mi & 1) * 4;
          unsigned short* dst =
              o2 + ((size_t)(bq * 16 + h) * 64 + ni * 16 + fr) * 1024 + baseL + p;
          *(u16x4*)dst = ov;
        }
      }
    }
  } else {
#pragma unroll
    for (int mi = 0; mi < 4; ++mi) {
#pragma unroll
      for (int ni = 0; ni < 4; ++ni) {
#pragma unroll
        for (int r = 0; r < 4; ++r) {
          int m = m0 + wm * 64 + mi * 16 + fg * 4 + r;
          int n = n0 + wn * 64 + ni * 16 + fr;
          float v = acc[mi][ni][r];
          if constexpr (EPI == 2) {
            float z = v + bias[n];
            float u = z * (0.7978845608f + 0.0356774081f * z * z);
            float e = __expf(2.f * u);
            float th = 1.f - 2.f / (e + 1.f);
            outp[(size_t)m * N + n] = f2b(0.5f * z * (1.f + th));
          } else {
            outp[(size_t)m * N + n] = f2b(v);
          }
        }
      }
    }
  }
#undef STQ3
#undef LDSV
}

// ---------- fc2 split-K reduce ----------
__global__ __launch_bounds__(256) void k_fc2red(const unsigned short* __restrict__ P0,
                                                const unsigned short* __restrict__ P1,
                                                const unsigned short* __restrict__ P2,
                                                const unsigned short* __restrict__ P3,
                                                const float* __restrict__ xmid,
                                                const float* __restrict__ bias,
                                                const float* __restrict__ ada,
                                                float* __restrict__ out) {
  size_t idx = ((size_t)blockIdx.x * 256 + threadIdx.x) * 8;
  int n = (int)(idx & 1023);
  int b = (int)(idx >> 20);
  u16x8 v0 = *(const u16x8*)(P0 + idx);
  u16x8 v1 = *(const u16x8*)(P1 + idx);
  u16x8 v2 = *(const u16x8*)(P2 + idx);
  u16x8 v3 = *(const u16x8*)(P3 + idx);
  const float* gp = ada + (size_t)b * 6144 + 1024 + n;
  const float* bp = bias + n;
  const float* xp = xmid + idx;
  float* op = out + idx;
#pragma unroll
  for (int i = 0; i < 8; ++i) {
    float sum = b2f(v0[i]) + b2f(v1[i]) + b2f(v2[i]) + b2f(v3[i]);
    op[i] = xp[i] + (sum + bp[i]) * gp[i];
  }
}

// ---------- 8-wave split-K GEMM (proj), NSTEPS template full-unroll ----------
template <int NSTEPS>
__global__ __launch_bounds__(512) void k_gemm8(const unsigned short* __restrict__ A,
                                               const unsigned short* __restrict__ W,
                                               int M, int N, int K,
                                               const float* __restrict__ bias,
                                               const float* __restrict__ resid,
                                               const float* __restrict__ ada,
                                               float* __restrict__ outp) {
  __shared__ unsigned short SM[49152];
  const int t = threadIdx.x, lane = t & 63, wv = t >> 6;
  const int grp = wv >> 2, w4 = wv & 3;
  const int wr = w4 >> 1, wc = w4 & 1;
  const int cpx = gridDim.x >> 3;
  const int orig = blockIdx.x;
  const int wid = (orig & 7) * cpx + (orig >> 3);
  const int nx = N >> 7;
  const int m0 = (wid / nx) * 128, n0 = (wid % nx) * 128;

  f32x4 zz = {0.f, 0.f, 0.f, 0.f};
  f32x4 acc[4][4];
#pragma unroll
  for (int i = 0; i < 4; ++i)
#pragma unroll
    for (int j = 0; j < 4; ++j) acc[i][j] = zz;

  const int Khalf = NSTEPS * 32;
  const int srow = lane >> 2, scol = (lane & 3) * 8;
  const int kbase = grp * Khalf;
  const unsigned short* aSrc0 = A + (size_t)(m0 + w4 * 16 + srow) * K + kbase + scol;
  const unsigned short* aSrc1 = aSrc0 + (size_t)64 * K;
  const unsigned short* bSrc0 = W + (size_t)(n0 + w4 * 16 + srow) * K + kbase + scol;
  const unsigned short* bSrc1 = bSrc0 + (size_t)64 * K;
  unsigned short* grpA = SM + grp * 24576;

  const int fr = lane & 15, fk = (lane >> 4) * 8;

#define STG8(buf_, k0_)                                                                            \
  {                                                                                                \
    __builtin_amdgcn_global_load_lds(AS1(aSrc0 + (k0_)), AS3(grpA + (buf_)*8192 + w4 * 512), 16, 0, 0); \
    __builtin_amdgcn_global_load_lds(AS1(aSrc1 + (k0_)), AS3(grpA + (buf_)*8192 + 2048 + w4 * 512), 16, 0, 0); \
    __builtin_amdgcn_global_load_lds(AS1(bSrc0 + (k0_)), AS3(grpA + (buf_)*8192 + 4096 + w4 * 512), 16, 0, 0); \
    __builtin_amdgcn_global_load_lds(AS1(bSrc1 + (k0_)), AS3(grpA + (buf_)*8192 + 6144 + w4 * 512), 16, 0, 0); \
  }

  STG8(0, 0);
  STG8(1, 32);
  asm volatile("s_waitcnt vmcnt(4)" ::: "memory");
  __builtin_amdgcn_s_barrier();

#pragma unroll
  for (int i = 0; i < NSTEPS; ++i) {
    const int buf = i % 3;
    if (i + 2 < NSTEPS) STG8((i + 2) % 3, (i + 2) * 32);
    const unsigned short* aRd = grpA + buf * 8192 + (wr * 64 + fr) * 32 + fk;
    const unsigned short* bRd = grpA + buf * 8192 + 4096 + (wc * 64 + fr) * 32 + fk;
    bf16x8 af[4], bfv[4];
#pragma unroll
    for (int q = 0; q < 4; ++q) af[q] = *(const bf16x8*)(aRd + q * 512);
#pragma unroll
    for (int q = 0; q < 4; ++q) bfv[q] = *(const bf16x8*)(bRd + q * 512);
    __builtin_amdgcn_s_setprio(1);
#pragma unroll
    for (int mi = 0; mi < 4; ++mi)
#pragma unroll
      for (int ni = 0; ni < 4; ++ni)
        acc[mi][ni] = __builtin_amdgcn_mfma_f32_16x16x32_bf16(af[mi], bfv[ni], acc[mi][ni], 0, 0, 0);
    __builtin_amdgcn_s_setprio(0);
    if (i < NSTEPS - 1) {
      if (i + 2 < NSTEPS) {
        asm volatile("s_waitcnt vmcnt(4)" ::: "memory");
      } else {
        asm volatile("s_waitcnt vmcnt(0)" ::: "memory");
      }
      __builtin_amdgcn_s_barrier();
    }
  }
  __syncthreads();

  float* xch = (float*)SM;
#pragma unroll
  for (int c = 0; c < 16; ++c) {
    if (grp == 1)
      *(f32x4*)&xch[c * 1024 + (w4 * 64 + lane) * 4] = acc[c >> 2][c & 3];
  }
  __syncthreads();
  if (grp == 1) return;
#pragma unroll
  for (int c = 0; c < 16; ++c) {
    f32x4 p = *(const f32x4*)&xch[c * 1024 + (w4 * 64 + lane) * 4];
    acc[c >> 2][c & 3] += p;
  }

  const int fg = lane >> 4;
#pragma unroll
  for (int mi = 0; mi < 4; ++mi) {
#pragma unroll
    for (int ni = 0; ni < 4; ++ni) {
#pragma unroll
      for (int r = 0; r < 4; ++r) {
        int m = m0 + wr * 64 + mi * 16 + fg * 4 + r;
        int n = n0 + wc * 64 + ni * 16 + fr;
        float v = acc[mi][ni][r];
        float g = ada[(size_t)(m >> 10) * 6144 + n];
        outp[(size_t)m * N + n] = resid[(size_t)m * N + n] + (v + bias[n]) * g;
      }
    }
  }
#undef STG8
}

// ---------- flash attention ----------
__global__ __launch_bounds__(256) void k_attn(const unsigned short* __restrict__ Qn,
                                              const unsigned short* __restrict__ Kn,
                                              const unsigned short* __restrict__ Vt,
                                              const float* __restrict__ smul,
                                              unsigned short* __restrict__ O) {
  const int qt = blockIdx.x, bh = blockIdx.y;
  const int b = bh >> 4, h = bh & 15;
  const int t = threadIdx.x, lane = t & 63, wv = t >> 6;
  const int fr = lane & 15, fg = lane >> 4;
  __shared__ unsigned short Kb[2][4096];
  __shared__ unsigned short Vb[2][4096];

  const int q0 = qt * 128 + wv * 32;
  const unsigned short* qp = Qn + ((size_t)bh * 1024 + q0 + fr) * 64 + fg * 8;
  bf16x8 qf00 = *(const bf16x8*)qp;
  bf16x8 qf01 = *(const bf16x8*)(qp + 32);
  bf16x8 qf10 = *(const bf16x8*)(qp + 1024);
  bf16x8 qf11 = *(const bf16x8*)(qp + 1024 + 32);

  const float M = __expf(fminf(smul[h], 4.6051701859880914f));

  const int srow = lane >> 3, sc = lane & 7;
  const int xr = (sc ^ srow) * 8;
  const unsigned short* kp0 = Kn + (size_t)bh * 65536 + (size_t)(wv * 16 + srow) * 64 + xr;
  const unsigned short* kp1 = kp0 + 8 * 64;
  const unsigned short* vp0 = Vt + (size_t)bh * 65536 + (size_t)(wv * 16 + srow) * 1024 + xr;
  const unsigned short* vp1 = vp0 + 8 * 1024;

  f32x4 zz = {0.f, 0.f, 0.f, 0.f};
  f32x4 oa0[4], oa1[4];
#pragma unroll
  for (int i = 0; i < 4; ++i) { oa0[i] = zz; oa1[i] = zz; }
  float ls0 = 0.f, ls1 = 0.f;

  {
    unsigned short* kd = &Kb[0][wv * 1024];
    unsigned short* vd = &Vb[0][wv * 1024];
    __builtin_amdgcn_global_load_lds(AS1(kp0), AS3(kd), 16, 0, 0);
    __builtin_amdgcn_global_load_lds(AS1(kp1), AS3(kd + 512), 16, 0, 0);
    __builtin_amdgcn_global_load_lds(AS1(vp0), AS3(vd), 16, 0, 0);
    __builtin_amdgcn_global_load_lds(AS1(vp1), AS3(vd + 512), 16, 0, 0);
  }
  __syncthreads();

  int cur = 0;
  for (int kv = 0; kv < 1024; kv += 64) {
    const int nxt = cur ^ 1;
    if (kv + 64 < 1024) {
      const int ko = (kv + 64) * 64;
      const int vo = kv + 64;
      unsigned short* kd = &Kb[nxt][wv * 1024];
      unsigned short* vd = &Vb[nxt][wv * 1024];
      __builtin_amdgcn_global_load_lds(AS1(kp0 + ko), AS3(kd), 16, 0, 0);
      __builtin_amdgcn_global_load_lds(AS1(kp1 + ko), AS3(kd + 512), 16, 0, 0);
      __builtin_amdgcn_global_load_lds(AS1(vp0 + vo), AS3(vd), 16, 0, 0);
      __builtin_amdgcn_global_load_lds(AS1(vp1 + vo), AS3(vd + 512), 16, 0, 0);
    }

    f32x4 s0[4], s1[4];
    __builtin_amdgcn_s_setprio(1);
#pragma unroll
    for (int ct = 0; ct < 4; ++ct) {
      const int row = ct * 16 + fr, r7 = row & 7;
      const unsigned short* kr = &Kb[cur][row * 64];
      bf16x8 kf0 = *(const bf16x8*)(kr + ((fg ^ r7) << 3));
      bf16x8 kf1 = *(const bf16x8*)(kr + (((4 + fg) ^ r7) << 3));
      f32x4 z0 = __builtin_amdgcn_mfma_f32_16x16x32_bf16(kf0, qf00, zz, 0, 0, 0);
      s0[ct] = __builtin_amdgcn_mfma_f32_16x16x32_bf16(kf1, qf01, z0, 0, 0, 0);
      f32x4 z1 = __builtin_amdgcn_mfma_f32_16x16x32_bf16(kf0, qf10, zz, 0, 0, 0);
      s1[ct] = __builtin_amdgcn_mfma_f32_16x16x32_bf16(kf1, qf11, z1, 0, 0, 0);
    }
    __builtin_amdgcn_s_setprio(0);

    bf16x8 pa0[2], pa1[2];
#pragma unroll
    for (int kg = 0; kg < 2; ++kg) {
      bf16x8 a0, a1;
#pragma unroll
      for (int c2 = 0; c2 < 2; ++c2) {
#pragma unroll
        for (int r = 0; r < 4; ++r) {
          float e0 = __expf(s0[kg * 2 + c2][r] - M);
          float e1 = __expf(s1[kg * 2 + c2][r] - M);
          ls0 += e0; ls1 += e1;
          a0[c2 * 4 + r] = (__bf16)e0;
          a1[c2 * 4 + r] = (__bf16)e1;
        }
      }
      pa0[kg] = a0; pa1[kg] = a1;
    }

    __builtin_amdgcn_s_setprio(1);
#pragma unroll
    for (int kg = 0; kg < 2; ++kg) {
#pragma unroll
      for (int dt = 0; dt < 4; ++dt) {
        const int row = dt * 16 + fr, r7 = row & 7;
        bf16x8 vf = *(const bf16x8*)(&Vb[cur][row * 64] + ((((kg << 2) + fg) ^ r7) << 3));
        oa0[dt] = __builtin_amdgcn_mfma_f32_16x16x32_bf16(pa0[kg], vf, oa0[dt], 0, 0, 0);
        oa1[dt] = __builtin_amdgcn_mfma_f32_16x16x32_bf16(pa1[kg], vf, oa1[dt], 0, 0, 0);
      }
    }
    __builtin_amdgcn_s_setprio(0);
    __syncthreads();
    cur = nxt;
  }

  ls0 += __shfl_xor(ls0, 16); ls0 += __shfl_xor(ls0, 32);
  ls1 += __shfl_xor(ls1, 16); ls1 += __shfl_xor(ls1, 32);

#pragma unroll
  for (int r = 0; r < 4; ++r) {
    float i0 = 1.f / __shfl(ls0, fg * 4 + r);
    float i1 = 1.f / __shfl(ls1, fg * 4 + r);
    unsigned short* ob = O + ((size_t)(b * 1024 + q0 + fg * 4 + r)) * 1024 + h * 64 + fr;
#pragma unroll
    for (int dt = 0; dt < 4; ++dt) {
      ob[dt * 16] = f2b(oa0[dt][r] * i0);
      ob[(size_t)16 * 1024 + dt * 16] = f2b(oa1[dt][r] * i1);
    }
  }
}

// ---------- launch ----------
extern "C" void kernel_launch(void* const* d_in, const int* in_sizes, int n_in,
                              void* d_out, int out_size, void* d_ws, size_t ws_size,
                              hipStream_t stream) {
  const float* x        = (const float*)d_in[0];
  const float* cond     = (const float*)d_in[1];
  const float* qkv_w    = (const float*)d_in[2];
  const float* q_bias   = (const float*)d_in[3];
  const float* v_bias   = (const float*)d_in[4];
  const float* scale_mul= (const float*)d_in[5];
  const float* proj_w   = (const float*)d_in[6];
  const float* proj_b   = (const float*)d_in[7];
  const float* ada_w    = (const float*)d_in[8];
  const float* ada_b    = (const float*)d_in[9];
  const float* fc1_w    = (const float*)d_in[10];
  const float* fc1_b    = (const float*)d_in[11];
  const float* fc2_w    = (const float*)d_in[12];
  const float* fc2_b    = (const float*)d_in[13];
  float* out = (float*)d_out;
  char* ws = (char*)d_ws;

  // ---- workspace map (lifetimes annotated; no live overlaps) ----
  unsigned short* WQ   = (unsigned short*)(ws + 0);          // dead after qkv
  unsigned short* WP   = (unsigned short*)(ws + 6291456);    // dead after proj
  unsigned short* WF1  = (unsigned short*)(ws + 8388608);    // dead after fc1
  unsigned short* WF2  = (unsigned short*)(ws + 16777216);   // dead after fc2 gemm
  float*          ADA  = (float*)(ws + 25182208);            // live throughout
  unsigned short* X1   = (unsigned short*)(ws + 25280512);   // dead after fc1
  float*          XMID = (float*)(ws + 42057728);            // live till fc2red
  unsigned short* QN   = (unsigned short*)(ws + 58834944);   // dead after attn
  unsigned short* KN   = (unsigned short*)(ws + 67223552);   // dead after attn
  unsigned short* VT   = (unsigned short*)(ws + 75612160);   // dead after attn
  unsigned short* OB   = (unsigned short*)(ws + 84000768);   // dead after proj
  unsigned short* HB   = (unsigned short*)(ws + 58834944);   // over QN/KN/VT/OB (dead by fc1)
  unsigned short* FP0  = (unsigned short*)(ws + 0);          // over WQ+WP (dead after proj)
  unsigned short* FP1  = (unsigned short*)(ws + 8388608);    // over WF1 (dead after fc1)
  unsigned short* FP2  = (unsigned short*)(ws + 25280512);   // over X1 (dead after fc1)
  unsigned short* FP3  = (unsigned short*)(ws + 33669120);   // free region (VB slot, unused now)

  (void)in_sizes; (void)n_in; (void)out_size; (void)ws_size;

  k_ada<<<1536, 256, 0, stream>>>(cond, ada_w, ada_b, ADA);
  k_castall<<<2048, 256, 0, stream>>>(qkv_w, proj_w, fc1_w, fc2_w, WQ, WP, WF1, WF2);

  k_ln_mod<<<4096, 256, 0, stream>>>(x, ADA, X1, 2, 4);
  // qkv: fused q/k norm epilogue + direct V^T write (no vtrans)
  k_gemm256<0, 1, 32><<<384, 512, 0, stream>>>(X1, WQ, 3072, 1024, 1024,
                                               scale_mul, q_bias, v_bias, QN, KN, VT, nullptr);
  k_attn<<<dim3(8, 64), 256, 0, stream>>>(QN, KN, VT, scale_mul, OB);
  k_gemm8<16><<<256, 512, 0, stream>>>(OB, WP, 4096, 1024, 1024,
                                       proj_b, x, ADA, XMID);
  k_ln_mod<<<4096, 256, 0, stream>>>(XMID, ADA, X1, 3, 5);
  k_gemm256<2, 1, 32><<<512, 512, 0, stream>>>(X1, WF1, 4096, 1024, 1024,
                                               fc1_b, nullptr, nullptr, HB, nullptr, nullptr, nullptr);
  k_gemm256<4, 4, 32><<<512, 512, 0, stream>>>(HB, WF2, 1024, 4096, 4096,
                                               nullptr, nullptr, nullptr, FP0, FP1, FP2, FP3);
  k_fc2red<<<2048, 256, 0, stream>>>(FP0, FP1, FP2, FP3, XMID, fc2_b, ADA, out);
}